// Round 10
// baseline (225.159 us; speedup 1.0000x reference)
//
#include <hip/hip_runtime.h>
#include <hip/hip_bf16.h>
#include <math.h>

#define B_N 4096
#define M_N 128
#define F_N 32
#define H_N 512
#define NFM 4096   // F*M

// wave-local LDS sync: all lanes of a wave run in lockstep, so a waitcnt on
// outstanding LDS ops makes prior cross-lane LDS writes visible to reads.
#define WAVE_SYNC() do { \
  asm volatile("s_waitcnt lgkmcnt(0)" ::: "memory"); \
  __builtin_amdgcn_sched_barrier(0); \
} while (0)

// ---------------------------------------------------------------------------
// Kernel 1: occupied-index extraction (wave ballot) + hidden layer.
// No atomics: writes the 128-bit occupancy mask per sample; buckets built
// deterministically by k_fill (fused count+fill), sorted by ascending b.
//   h[b,:] = tanhf( sum_j W1[idx_j,:] + b1 )   (ascending-j chain, fp32)
// ---------------------------------------------------------------------------
__global__ __launch_bounds__(256) void k1_idx_h(
    const float* __restrict__ n, const float* __restrict__ W1,
    const float* __restrict__ b1, float* __restrict__ h_ws,
    unsigned int* __restrict__ mask)
{
  __shared__ int s_idx[F_N];
  __shared__ int s_cnt0;
  const int b = blockIdx.x;
  const int t = threadIdx.x;

  bool p = false;
  int before = 0;
  if (t < 128) {
    float v = n[(size_t)b * M_N + t];
    p = v > 0.5f;
    unsigned long long m = __ballot(p);
    int lane = t & 63;
    before = __popcll(m & ((1ull << lane) - 1ull));
    if (lane == 0) {
      if (t < 64) { mask[b*4+0] = (unsigned)m; mask[b*4+1] = (unsigned)(m>>32); }
      else        { mask[b*4+2] = (unsigned)m; mask[b*4+3] = (unsigned)(m>>32); }
    }
    if (t < 64) {
      if (lane == 0) s_cnt0 = __popcll(m);
      if (p) s_idx[before] = t;          // ascending within wave 0
    }
  }
  __syncthreads();
  if (t >= 64 && t < 128 && p) s_idx[s_cnt0 + before] = t;
  __syncthreads();

  #pragma unroll
  for (int cc = 0; cc < 2; ++cc) {
    int c = t + cc * 256;
    float acc = 0.0f;
    #pragma unroll
    for (int j = 0; j < F_N; ++j)
      acc += W1[(size_t)s_idx[j] * H_N + c];
    acc += b1[c];                        // b1 = zeros: exact
    h_ws[(size_t)b * H_N + c] = tanhf(acc);
  }
}

// ---------------------------------------------------------------------------
// k_w2t: pre-transpose W2 into bucket-friendly layout:
//   W2t[c*H_N*F_N + k*F_N + ig] = W2[k*NFM + ig*M_N + c]
// (round 9: killed the 128 MB in-k2 column-gather line amplification)
// ---------------------------------------------------------------------------
__global__ __launch_bounds__(256) void k_w2t(
    const float* __restrict__ W2, float* __restrict__ W2t)
{
  __shared__ float lds[32 * 132];
  const int k = blockIdx.x;
  const int t = threadIdx.x;

  #pragma unroll
  for (int i = 0; i < 4; ++i) {
    int m0 = i * 1024 + t * 4;             // never crosses a 128 boundary
    float4 v = *(const float4*)&W2[(size_t)k * NFM + m0];
    int ig = m0 >> 7, c = m0 & 127;
    lds[ig * 132 + c + 0] = v.x;
    lds[ig * 132 + c + 1] = v.y;
    lds[ig * 132 + c + 2] = v.z;
    lds[ig * 132 + c + 3] = v.w;
  }
  __syncthreads();

  const int c  = t >> 1;
  const int ih = (t & 1) * 16;
  float* outp = W2t + (size_t)c * (H_N * F_N) + k * F_N + ih;
  #pragma unroll
  for (int i = 0; i < 4; ++i) {
    int ig = ih + i * 4;
    float4 v = make_float4(lds[(ig + 0) * 132 + c], lds[(ig + 1) * 132 + c],
                           lds[(ig + 2) * 132 + c], lds[(ig + 3) * 132 + c]);
    *(float4*)(outp + i * 4) = v;
  }
}

// ---------------------------------------------------------------------------
// k_fill (ROUND 21: fused count+fill, one kernel instead of two):
// Pass 1: block c computes cnt_c = sum_b bit_c(b) AND boff_c = sum_b
//   rank_b(c) (= sum_{i<c} cnt_i, since rank counts occupied orbitals < c).
//   This removes k_count and the O(c) serial prefix loop.
// Pass 2: deterministic fill, entries sorted by ascending sample b:
//   bent[c*B_N + pos] = (b<<5) | j ;  loc[b*32 + j] = boff_c + pos
// ---------------------------------------------------------------------------
__global__ __launch_bounds__(256) void k_fill(
    const unsigned int* __restrict__ mask,
    int* __restrict__ bcnt, int* __restrict__ boff,
    int* __restrict__ bent, int* __restrict__ loc)
{
  const int c = blockIdx.x;
  const int t = threadIdx.x;
  const int w = t >> 6, lane = t & 63;
  const int word = c >> 5, bit = c & 31;
  __shared__ int s_wcnt[4];
  __shared__ int s_red[8];
  __shared__ int s_run;

  // ---- pass 1: count + offset ----
  int cnt_loc = 0, off_loc = 0;
  for (int b = t; b < B_N; b += 256) {
    unsigned m0 = mask[(size_t)b*4+0], m1 = mask[(size_t)b*4+1];
    unsigned m2 = mask[(size_t)b*4+2], m3 = mask[(size_t)b*4+3];
    unsigned wv = (word == 0) ? m0 : (word == 1) ? m1 : (word == 2) ? m2 : m3;
    cnt_loc += (int)((wv >> bit) & 1u);
    int r = __popc(wv & ((1u << bit) - 1u));
    if (word > 0) r += __popc(m0);
    if (word > 1) r += __popc(m1);
    if (word > 2) r += __popc(m2);
    off_loc += r;
  }
  #pragma unroll
  for (int off = 32; off > 0; off >>= 1) {
    cnt_loc += __shfl_down(cnt_loc, off);
    off_loc += __shfl_down(off_loc, off);
  }
  if (lane == 0) { s_red[w] = cnt_loc; s_red[4 + w] = off_loc; }
  __syncthreads();
  const int cnt_tot = s_red[0] + s_red[1] + s_red[2] + s_red[3];
  const int off_tot = s_red[4] + s_red[5] + s_red[6] + s_red[7];
  if (t == 0) { bcnt[c] = cnt_tot; boff[c] = off_tot; s_run = 0; }
  __syncthreads();

  // ---- pass 2: fill (ascending b) ----
  for (int chunk = 0; chunk < B_N; chunk += 256) {
    const int b = chunk + t;
    unsigned m0 = mask[(size_t)b*4+0], m1 = mask[(size_t)b*4+1];
    unsigned m2 = mask[(size_t)b*4+2], m3 = mask[(size_t)b*4+3];
    unsigned wv = (word == 0) ? m0 : (word == 1) ? m1 : (word == 2) ? m2 : m3;
    bool p = (wv >> bit) & 1u;
    int j = __popc(wv & ((1u << bit) - 1u));
    if (word > 0) j += __popc(m0);
    if (word > 1) j += __popc(m1);
    if (word > 2) j += __popc(m2);

    unsigned long long bal = __ballot(p);
    int before = __popcll(bal & ((1ull << lane) - 1ull));
    if (lane == 0) s_wcnt[w] = __popcll(bal);
    __syncthreads();
    int wbase = s_run;
    for (int i = 0; i < w; ++i) wbase += s_wcnt[i];
    if (p) {
      int pos = wbase + before;              // bucket-local, ascending b
      bent[(size_t)c * B_N + pos] = (b << 5) | j;
      loc[b * 32 + j] = off_tot + pos;
    }
    __syncthreads();
    if (t == 0) s_run += s_wcnt[0] + s_wcnt[1] + s_wcnt[2] + s_wcnt[3];
    __syncthreads();
  }
}

// ---------------------------------------------------------------------------
// Kernel 2 (ROUND 21): BUCKETED GEMM, 8x4 micro-tile.
// Round 9 post-mortem: 4x4 micro-tile = 2 B of LDS per lane-fma; the CU LDS
// return path sustains ~85 B/cy vs 128 lane-fma/cy VALU -> VALUBusy cap
// 0.66/2.0 = 33%; measured 37.6% = AT the cap. 8x4 (tile 256x32, 256 thr,
// 3 ds_read_b128 per 32 fma = 1.5 B/fma) lifts the cap to ~44% while
// keeping 8.5 waves/CU (grid ~550 x 4 waves) for latency hiding.
// B panel from W2t (contiguous, L2-resident), b-sorted entries, bucket-major
// phi writes — unchanged from round 9.
// ARITHMETIC BIT-IDENTICAL: each output = one ascending-k fmaf chain
// (t ascending, kk ascending, single accumulator); epilogue Phi + (acc + b2)
// unchanged. absmax must stay exactly 0.203125.
// ---------------------------------------------------------------------------
__global__ __launch_bounds__(256) void k2_gemm_gather(
    const float* __restrict__ h, const float* __restrict__ W2t,
    const float* __restrict__ b2, const float* __restrict__ Phi,
    const int* __restrict__ bcnt, const int* __restrict__ boff,
    const int* __restrict__ bent, float* __restrict__ phi_bucket)
{
  // per buffer: At [16][260] = 4160 floats + Bt [16][32] = 512 -> 4672
  __shared__ __align__(16) float smem[2 * 4672];   // 37376 B
  __shared__ int s_b[256];

  const int tid = threadIdx.x;               // 0..255
  const int c   = blockIdx.x;                // orbital 0..127
  const int cnt = bcnt[c];
  const int t0  = blockIdx.y * 256;          // row-tile base within bucket
  if (t0 >= cnt) return;                     // block-uniform early exit
  const int base = boff[c];
  const float* w2tc = W2t + (size_t)c * (H_N * F_N);

  {
    int ii = t0 + tid;
    int e  = bent[(size_t)c * B_N + (ii < cnt ? ii : cnt - 1)];  // cnt >= 1
    s_b[tid] = e >> 5;
  }
  __syncthreads();

  const int kA  = tid & 15;                  // A stage: kk (0..15)
  const int rgA = tid >> 4;                  // A stage: row group (0..15)
  const int tx  = tid & 7;                   // col group: igs tx*4..+3
  const int tyr = tid >> 3;                  // row group 0..31: rows tyr*8..+7

  int rowb[16];
  #pragma unroll
  for (int i = 0; i < 16; ++i) rowb[i] = s_b[rgA * 16 + i];

  float acc[8][4];
  #pragma unroll
  for (int i = 0; i < 8; ++i)
    #pragma unroll
    for (int u = 0; u < 4; ++u) acc[i][u] = 0.f;

  float aReg[16], bReg0, bReg1;

  // ---- prologue: stage k-tile 0 into buf0 ----
  #pragma unroll
  for (int i = 0; i < 16; ++i)
    aReg[i] = h[(size_t)rowb[i] * H_N + kA];
  bReg0 = w2tc[tid];                         // Bt rows 0..7  (linear)
  bReg1 = w2tc[256 + tid];                   // Bt rows 8..15
  #pragma unroll
  for (int u = 0; u < 4; ++u)
    *(float4*)&smem[kA * 260 + rgA * 16 + u * 4] =
        make_float4(aReg[4*u], aReg[4*u+1], aReg[4*u+2], aReg[4*u+3]);
  smem[4160 + tid] = bReg0;
  smem[4160 + 256 + tid] = bReg1;
  __syncthreads();

  #pragma unroll 1
  for (int t = 0; t < 32; ++t) {
    float* Atc = smem + (t & 1) * 4672;
    float* Btc = Atc + 4160;
    float* Atn = smem + ((t + 1) & 1) * 4672;
    float* Btn = Atn + 4160;

    // issue next tile's global loads (latency hides under compute)
    if (t < 31) {
      int k0n = (t + 1) * 16;
      #pragma unroll
      for (int i = 0; i < 16; ++i)
        aReg[i] = h[(size_t)rowb[i] * H_N + k0n + kA];
      bReg0 = w2tc[k0n * 32 + tid];
      bReg1 = w2tc[k0n * 32 + 256 + tid];
    }

    // compute tile t: 3 x ds_read_b128 + 32 fmaf per kk (1.5 B/fma)
    #pragma unroll
    for (int kk = 0; kk < 16; ++kk) {
      float4 a0 = *(const float4*)&Atc[kk * 260 + tyr * 8];
      float4 a1 = *(const float4*)&Atc[kk * 260 + tyr * 8 + 4];
      float4 bv = *(const float4*)&Btc[kk * 32 + tx * 4];
      float a8[8] = {a0.x, a0.y, a0.z, a0.w, a1.x, a1.y, a1.z, a1.w};
      float b4[4] = {bv.x, bv.y, bv.z, bv.w};
      #pragma unroll
      for (int i = 0; i < 8; ++i)
        #pragma unroll
        for (int u = 0; u < 4; ++u)
          acc[i][u] = fmaf(a8[i], b4[u], acc[i][u]);
    }

    // stage tile t+1 into the idle buffer; single barrier flips
    if (t < 31) {
      #pragma unroll
      for (int u = 0; u < 4; ++u)
        *(float4*)&Atn[kA * 260 + rgA * 16 + u * 4] =
            make_float4(aReg[4*u], aReg[4*u+1], aReg[4*u+2], aReg[4*u+3]);
      Btn[tid] = bReg0;
      Btn[256 + tid] = bReg1;
      __syncthreads();
    }
  }

  // ---- epilogue: coalesced float4 writes into bucket-major phi ----
  float ph[4], bb[4];
  #pragma unroll
  for (int u = 0; u < 4; ++u) {
    int colw = (tx * 4 + u) * M_N + c;
    ph[u] = Phi[colw];
    bb[u] = b2[colw];
  }
  #pragma unroll
  for (int i = 0; i < 8; ++i) {
    int r = tyr * 8 + i;
    if (t0 + r < cnt) {
      int col = base + t0 + r;               // global column index
      float v0 = ph[0] + (acc[i][0] + bb[0]);
      float v1 = ph[1] + (acc[i][1] + bb[1]);
      float v2 = ph[2] + (acc[i][2] + bb[2]);
      float v3 = ph[3] + (acc[i][3] + bb[3]);
      *(float4*)&phi_bucket[(size_t)col * 32 + tx * 4] =
          make_float4(v0, v1, v2, v3);
    }
  }
}

// ---------------------------------------------------------------------------
// Kernel 3: batched 32x32 fp32 LU replicating LAPACK sgetf2 exactly.
// ROUND 21: the rank-1 update now uses BOTH 32-lane halves — lane j does
// rows [k+1, mid), lane j+32 does rows [mid, 32) of column j. Elements
// within one iteration k are independent and each element's fmaf is
// unchanged -> bit-identical, ~2x less serial depth on the dominant phase.
// Loads columns from bucket-major phi_bucket via loc (contiguous 128 B).
// PLANAR complex output: out[0..B-1] = log|det|, out[B..2B-1] = arg(sign)
// ---------------------------------------------------------------------------
__global__ __launch_bounds__(256) void k3_det(
    const float* __restrict__ phi_bucket, const int* __restrict__ loc,
    float* __restrict__ out)
{
  __shared__ float A[4][32 * 33];
  const int w = threadIdx.x >> 6;
  const int lane = threadIdx.x & 63;
  const int b = blockIdx.x * 4 + w;
  float* Aw = A[w];

  {
    const int jj = lane & 31;
    const int hi = lane >> 5;              // 0 or 1: ig halves
    int lcol = loc[b * 32 + jj];
    const float* colp = phi_bucket + (size_t)lcol * 32 + hi * 16;
    #pragma unroll
    for (int i = 0; i < 4; ++i) {
      float4 v = *(const float4*)(colp + i * 4);
      int ig = hi * 16 + i * 4;
      Aw[(ig + 0) * 33 + jj] = v.x;
      Aw[(ig + 1) * 33 + jj] = v.y;
      Aw[(ig + 2) * 33 + jj] = v.z;
      Aw[(ig + 3) * 33 + jj] = v.w;
    }
  }
  WAVE_SYNC();

  float logabs = 0.f;
  int negs = 0;
  for (int k = 0; k < 32; ++k) {
    // isamax over rows k..31 of column k (ties -> first index)
    float v = -1.f;
    int vi = lane;
    if (lane >= k && lane < 32) v = fabsf(Aw[lane * 33 + k]);
    #pragma unroll
    for (int off = 32; off > 0; off >>= 1) {
      float ov = __shfl_xor(v, off);
      int oi = __shfl_xor(vi, off);
      if (ov > v || (ov == v && oi < vi)) { v = ov; vi = oi; }
    }
    int p = vi;                          // uniform across the wave
    if (p != k) {
      negs ^= 1;
      if (lane < 32) {
        float tmp = Aw[k * 33 + lane];
        Aw[k * 33 + lane] = Aw[p * 33 + lane];
        Aw[p * 33 + lane] = tmp;
      }
    }
    WAVE_SYNC();
    float piv = Aw[k * 33 + k];
    if (piv < 0.f) negs ^= 1;
    logabs += logf(fabsf(piv));
    if (lane > k && lane < 32) {
      float l = Aw[lane * 33 + k];
      if (fabsf(piv) >= 1.17549435e-38f) l = l * (1.0f / piv);  // sscal path
      else                               l = l / piv;           // tiny pivot
      Aw[lane * 33 + k] = l;
    }
    WAVE_SYNC();
    {
      const int mid = (k + 33) >> 1;         // balanced split of k+1..31
      const int j   = lane & 31;
      const int ilo = (lane < 32) ? (k + 1) : mid;
      const int ihi = (lane < 32) ? mid : 32;
      if (j > k) {
        float nukj = -Aw[k * 33 + j];
        for (int i = ilo; i < ihi; ++i)
          Aw[i * 33 + j] = fmaf(nukj, Aw[i * 33 + k], Aw[i * 33 + j]);
      }
    }
    WAVE_SYNC();
  }

  if (lane == 0) {
    out[b]       = logabs;                                   // Re: log|det|
    out[B_N + b] = (negs & 1) ? 3.14159265358979f : 0.0f;    // Im: arg(sign)
  }
}

// ---------------------------------------------------------------------------
extern "C" void kernel_launch(void* const* d_in, const int* in_sizes, int n_in,
                              void* d_out, int out_size, void* d_ws, size_t ws_size,
                              hipStream_t stream) {
  const float* n   = (const float*)d_in[0];
  const float* Phi = (const float*)d_in[1];
  const float* W1  = (const float*)d_in[2];
  const float* b1  = (const float*)d_in[3];
  const float* W2  = (const float*)d_in[4];
  const float* b2  = (const float*)d_in[5];
  float* out = (float*)d_out;

  char* ws = (char*)d_ws;
  float*        h_ws       = (float*)ws;                                  // 8 MB
  float*        phi_bucket = (float*)(ws + (size_t)8  * 1024 * 1024);     // 16 MB
  float*        W2t        = (float*)(ws + (size_t)24 * 1024 * 1024);     // 8 MB
  unsigned int* mask       = (unsigned int*)(ws + (size_t)32 * 1024 * 1024); // 64 KB
  int*          bent       = (int*)(ws + (size_t)32 * 1024 * 1024 + 65536);  // 2 MB
  int*          loc        = (int*)(ws + (size_t)34 * 1024 * 1024 + 65536);  // 512 KB
  int*          bcnt       = (int*)(ws + (size_t)34 * 1024 * 1024 + 65536 + 524288);
  int*          boff       = (int*)(ws + (size_t)34 * 1024 * 1024 + 65536 + 524288 + 4096);

  hipLaunchKernelGGL(k_w2t, dim3(H_N), dim3(256), 0, stream, W2, W2t);
  hipLaunchKernelGGL(k1_idx_h, dim3(B_N), dim3(256), 0, stream,
                     n, W1, b1, h_ws, mask);
  hipLaunchKernelGGL(k_fill, dim3(M_N), dim3(256), 0, stream,
                     mask, bcnt, boff, bent, loc);
  hipLaunchKernelGGL(k2_gemm_gather, dim3(M_N, 16), dim3(256), 0, stream,
                     h_ws, W2t, b2, Phi, bcnt, boff, bent, phi_bucket);
  hipLaunchKernelGGL(k3_det, dim3(B_N / 4), dim3(256), 0, stream,
                     phi_bucket, loc, out);
}

// Round 11
// 192.957 us; speedup vs baseline: 1.1669x; 1.1669x over previous
//
#include <hip/hip_runtime.h>
#include <hip/hip_bf16.h>
#include <math.h>

#define B_N 4096
#define M_N 128
#define F_N 32
#define H_N 512
#define NFM 4096   // F*M

// wave-local LDS sync: all lanes of a wave run in lockstep, so a waitcnt on
// outstanding LDS ops makes prior cross-lane LDS writes visible to reads.
#define WAVE_SYNC() do { \
  asm volatile("s_waitcnt lgkmcnt(0)" ::: "memory"); \
  __builtin_amdgcn_sched_barrier(0); \
} while (0)

// ---------------------------------------------------------------------------
// Kernel 1: occupied-index extraction (wave ballot) + hidden layer.
// No atomics: writes the 128-bit occupancy mask per sample; buckets built
// deterministically by k_fill (fused count+fill), sorted by ascending b.
//   h[b,:] = tanhf( sum_j W1[idx_j,:] + b1 )   (ascending-j chain, fp32)
// ---------------------------------------------------------------------------
__global__ __launch_bounds__(256) void k1_idx_h(
    const float* __restrict__ n, const float* __restrict__ W1,
    const float* __restrict__ b1, float* __restrict__ h_ws,
    unsigned int* __restrict__ mask)
{
  __shared__ int s_idx[F_N];
  __shared__ int s_cnt0;
  const int b = blockIdx.x;
  const int t = threadIdx.x;

  bool p = false;
  int before = 0;
  if (t < 128) {
    float v = n[(size_t)b * M_N + t];
    p = v > 0.5f;
    unsigned long long m = __ballot(p);
    int lane = t & 63;
    before = __popcll(m & ((1ull << lane) - 1ull));
    if (lane == 0) {
      if (t < 64) { mask[b*4+0] = (unsigned)m; mask[b*4+1] = (unsigned)(m>>32); }
      else        { mask[b*4+2] = (unsigned)m; mask[b*4+3] = (unsigned)(m>>32); }
    }
    if (t < 64) {
      if (lane == 0) s_cnt0 = __popcll(m);
      if (p) s_idx[before] = t;          // ascending within wave 0
    }
  }
  __syncthreads();
  if (t >= 64 && t < 128 && p) s_idx[s_cnt0 + before] = t;
  __syncthreads();

  #pragma unroll
  for (int cc = 0; cc < 2; ++cc) {
    int c = t + cc * 256;
    float acc = 0.0f;
    #pragma unroll
    for (int j = 0; j < F_N; ++j)
      acc += W1[(size_t)s_idx[j] * H_N + c];
    acc += b1[c];                        // b1 = zeros: exact
    h_ws[(size_t)b * H_N + c] = tanhf(acc);
  }
}

// ---------------------------------------------------------------------------
// k_w2t: pre-transpose W2 into bucket-friendly layout:
//   W2t[c*H_N*F_N + k*F_N + ig] = W2[k*NFM + ig*M_N + c]
// (round 9: killed the 128 MB in-k2 column-gather line amplification)
// ---------------------------------------------------------------------------
__global__ __launch_bounds__(256) void k_w2t(
    const float* __restrict__ W2, float* __restrict__ W2t)
{
  __shared__ float lds[32 * 132];
  const int k = blockIdx.x;
  const int t = threadIdx.x;

  #pragma unroll
  for (int i = 0; i < 4; ++i) {
    int m0 = i * 1024 + t * 4;             // never crosses a 128 boundary
    float4 v = *(const float4*)&W2[(size_t)k * NFM + m0];
    int ig = m0 >> 7, c = m0 & 127;
    lds[ig * 132 + c + 0] = v.x;
    lds[ig * 132 + c + 1] = v.y;
    lds[ig * 132 + c + 2] = v.z;
    lds[ig * 132 + c + 3] = v.w;
  }
  __syncthreads();

  const int c  = t >> 1;
  const int ih = (t & 1) * 16;
  float* outp = W2t + (size_t)c * (H_N * F_N) + k * F_N + ih;
  #pragma unroll
  for (int i = 0; i < 4; ++i) {
    int ig = ih + i * 4;
    float4 v = make_float4(lds[(ig + 0) * 132 + c], lds[(ig + 1) * 132 + c],
                           lds[(ig + 2) * 132 + c], lds[(ig + 3) * 132 + c]);
    *(float4*)(outp + i * 4) = v;
  }
}

// ---------------------------------------------------------------------------
// k_fill (fused count+fill):
// Pass 1: block c computes cnt_c AND boff_c = sum_b rank_b(c) directly.
// Pass 2: deterministic fill, entries sorted by ascending sample b:
//   bent[c*B_N + pos] = (b<<5) | j ;  loc[b*32 + j] = boff_c + pos
// ---------------------------------------------------------------------------
__global__ __launch_bounds__(256) void k_fill(
    const unsigned int* __restrict__ mask,
    int* __restrict__ bcnt, int* __restrict__ boff,
    int* __restrict__ bent, int* __restrict__ loc)
{
  const int c = blockIdx.x;
  const int t = threadIdx.x;
  const int w = t >> 6, lane = t & 63;
  const int word = c >> 5, bit = c & 31;
  __shared__ int s_wcnt[4];
  __shared__ int s_red[8];
  __shared__ int s_run;

  // ---- pass 1: count + offset ----
  int cnt_loc = 0, off_loc = 0;
  for (int b = t; b < B_N; b += 256) {
    unsigned m0 = mask[(size_t)b*4+0], m1 = mask[(size_t)b*4+1];
    unsigned m2 = mask[(size_t)b*4+2], m3 = mask[(size_t)b*4+3];
    unsigned wv = (word == 0) ? m0 : (word == 1) ? m1 : (word == 2) ? m2 : m3;
    cnt_loc += (int)((wv >> bit) & 1u);
    int r = __popc(wv & ((1u << bit) - 1u));
    if (word > 0) r += __popc(m0);
    if (word > 1) r += __popc(m1);
    if (word > 2) r += __popc(m2);
    off_loc += r;
  }
  #pragma unroll
  for (int off = 32; off > 0; off >>= 1) {
    cnt_loc += __shfl_down(cnt_loc, off);
    off_loc += __shfl_down(off_loc, off);
  }
  if (lane == 0) { s_red[w] = cnt_loc; s_red[4 + w] = off_loc; }
  __syncthreads();
  const int cnt_tot = s_red[0] + s_red[1] + s_red[2] + s_red[3];
  const int off_tot = s_red[4] + s_red[5] + s_red[6] + s_red[7];
  if (t == 0) { bcnt[c] = cnt_tot; boff[c] = off_tot; s_run = 0; }
  __syncthreads();

  // ---- pass 2: fill (ascending b) ----
  for (int chunk = 0; chunk < B_N; chunk += 256) {
    const int b = chunk + t;
    unsigned m0 = mask[(size_t)b*4+0], m1 = mask[(size_t)b*4+1];
    unsigned m2 = mask[(size_t)b*4+2], m3 = mask[(size_t)b*4+3];
    unsigned wv = (word == 0) ? m0 : (word == 1) ? m1 : (word == 2) ? m2 : m3;
    bool p = (wv >> bit) & 1u;
    int j = __popc(wv & ((1u << bit) - 1u));
    if (word > 0) j += __popc(m0);
    if (word > 1) j += __popc(m1);
    if (word > 2) j += __popc(m2);

    unsigned long long bal = __ballot(p);
    int before = __popcll(bal & ((1ull << lane) - 1ull));
    if (lane == 0) s_wcnt[w] = __popcll(bal);
    __syncthreads();
    int wbase = s_run;
    for (int i = 0; i < w; ++i) wbase += s_wcnt[i];
    if (p) {
      int pos = wbase + before;              // bucket-local, ascending b
      bent[(size_t)c * B_N + pos] = (b << 5) | j;
      loc[b * 32 + j] = off_tot + pos;
    }
    __syncthreads();
    if (t == 0) s_run += s_wcnt[0] + s_wcnt[1] + s_wcnt[2] + s_wcnt[3];
    __syncthreads();
  }
}

// ---------------------------------------------------------------------------
// Kernel 2 (ROUND 22): BUCKETED GEMM, 8x4 micro-tile DONE RIGHT.
// Round 10 post-mortem: 8x4 with 256-thread/256-row blocks failed on
//   occupancy (VGPR 148 -> 3 w/SIMD bracket; 512 real blocks = 2/CU; 16
//   scattered A loads/thread) — VALUBusy 27% << the 44% cap. The LDS cap
//   model held (round 9's 4x4 = cap 33%, measured 37.6).
// ROUND 22 fixes all three while keeping the 8x4 cap:
//   128 THREADS (2 waves), tile 128x32, BK=8:
//   - grid 128 x 16 y-tiles -> ~1100 real blocks = 8+ waves/CU
//   - A-stage 8 rows/thread (rowb[8], aReg[8]) -> VGPR ~90-105 (4w bracket)
//   - LDS 2 x (At[8][132]+Bt[8][32]) = 10.5 KB
//   - 2-wave barriers (round-4 pattern: cheap, 4+ independent blocks/CU)
// Per kk: 3 ds_read_b128 per 32 fma -> cap rc/(6(r+c)) = 44% VALUBusy.
// ARITHMETIC BIT-IDENTICAL: global k = 8t+kk ascending, single accumulator
// per output; epilogue Phi + (acc + b2) unchanged. absmax == 0.203125.
// ---------------------------------------------------------------------------
__global__ __launch_bounds__(128) void k2_gemm_gather(
    const float* __restrict__ h, const float* __restrict__ W2t,
    const float* __restrict__ b2, const float* __restrict__ Phi,
    const int* __restrict__ bcnt, const int* __restrict__ boff,
    const int* __restrict__ bent, float* __restrict__ phi_bucket)
{
  // per buffer: At [8][132] = 1056 floats + Bt [8][32] = 256 -> 1312
  __shared__ __align__(16) float smem[2 * 1312];   // 10496 B
  __shared__ int s_b[128];

  const int tid = threadIdx.x;               // 0..127
  const int c   = blockIdx.x;                // orbital 0..127
  const int cnt = bcnt[c];
  const int t0  = blockIdx.y * 128;          // row-tile base within bucket
  if (t0 >= cnt) return;                     // block-uniform early exit
  const int base = boff[c];
  const float* w2tc = W2t + (size_t)c * (H_N * F_N);

  {
    int ii = t0 + tid;
    int e  = bent[(size_t)c * B_N + (ii < cnt ? ii : cnt - 1)];  // cnt >= 1
    s_b[tid] = e >> 5;
  }
  __syncthreads();

  const int kA  = tid & 7;                   // A stage: kk (0..7)
  const int rgA = tid >> 3;                  // A/compute row group (0..15)
  const int tx  = tid & 7;                   // col group: igs tx*4..+3
  const int r8  = rgA * 8;                   // rows r8..r8+7

  int rowb[8];
  #pragma unroll
  for (int i = 0; i < 8; ++i) rowb[i] = s_b[r8 + i];

  float acc[8][4];
  #pragma unroll
  for (int i = 0; i < 8; ++i)
    #pragma unroll
    for (int u = 0; u < 4; ++u) acc[i][u] = 0.f;

  float aReg[8], bReg0, bReg1;

  // ---- prologue: stage k-tile 0 into buf0 ----
  #pragma unroll
  for (int i = 0; i < 8; ++i)
    aReg[i] = h[(size_t)rowb[i] * H_N + kA];
  bReg0 = w2tc[tid];                         // Bt kk 0..3  (linear 128)
  bReg1 = w2tc[128 + tid];                   // Bt kk 4..7
  #pragma unroll
  for (int u = 0; u < 2; ++u)
    *(float4*)&smem[kA * 132 + r8 + u * 4] =
        make_float4(aReg[4*u], aReg[4*u+1], aReg[4*u+2], aReg[4*u+3]);
  smem[1056 + tid] = bReg0;
  smem[1056 + 128 + tid] = bReg1;
  __syncthreads();

  #pragma unroll 1
  for (int t = 0; t < 64; ++t) {
    float* Atc = smem + (t & 1) * 1312;
    float* Btc = Atc + 1056;
    float* Atn = smem + ((t + 1) & 1) * 1312;
    float* Btn = Atn + 1056;

    // issue next tile's global loads (latency hides under compute)
    if (t < 63) {
      int k0n = (t + 1) * 8;
      #pragma unroll
      for (int i = 0; i < 8; ++i)
        aReg[i] = h[(size_t)rowb[i] * H_N + k0n + kA];
      bReg0 = w2tc[k0n * 32 + tid];
      bReg1 = w2tc[k0n * 32 + 128 + tid];
    }

    // compute tile t: 3 x ds_read_b128 + 32 fmaf per kk (1.5 B/fma)
    #pragma unroll
    for (int kk = 0; kk < 8; ++kk) {
      float4 a0 = *(const float4*)&Atc[kk * 132 + r8];
      float4 a1 = *(const float4*)&Atc[kk * 132 + r8 + 4];
      float4 bv = *(const float4*)&Btc[kk * 32 + tx * 4];
      float a8[8] = {a0.x, a0.y, a0.z, a0.w, a1.x, a1.y, a1.z, a1.w};
      float b4[4] = {bv.x, bv.y, bv.z, bv.w};
      #pragma unroll
      for (int i = 0; i < 8; ++i)
        #pragma unroll
        for (int u = 0; u < 4; ++u)
          acc[i][u] = fmaf(a8[i], b4[u], acc[i][u]);
    }

    // stage tile t+1 into the idle buffer; single barrier flips
    if (t < 63) {
      #pragma unroll
      for (int u = 0; u < 2; ++u)
        *(float4*)&Atn[kA * 132 + r8 + u * 4] =
            make_float4(aReg[4*u], aReg[4*u+1], aReg[4*u+2], aReg[4*u+3]);
      Btn[tid] = bReg0;
      Btn[128 + tid] = bReg1;
      __syncthreads();
    }
  }

  // ---- epilogue: coalesced float4 writes into bucket-major phi ----
  float ph[4], bb[4];
  #pragma unroll
  for (int u = 0; u < 4; ++u) {
    int colw = (tx * 4 + u) * M_N + c;
    ph[u] = Phi[colw];
    bb[u] = b2[colw];
  }
  #pragma unroll
  for (int i = 0; i < 8; ++i) {
    int r = r8 + i;
    if (t0 + r < cnt) {
      int col = base + t0 + r;               // global column index
      float v0 = ph[0] + (acc[i][0] + bb[0]);
      float v1 = ph[1] + (acc[i][1] + bb[1]);
      float v2 = ph[2] + (acc[i][2] + bb[2]);
      float v3 = ph[3] + (acc[i][3] + bb[3]);
      *(float4*)&phi_bucket[(size_t)col * 32 + tx * 4] =
          make_float4(v0, v1, v2, v3);
    }
  }
}

// ---------------------------------------------------------------------------
// Kernel 3: batched 32x32 fp32 LU replicating LAPACK sgetf2 exactly.
// Rank-1 update uses BOTH 32-lane halves (rows split [k+1,mid)/[mid,32);
// elements within an iteration are independent -> bit-identical).
// Loads columns from bucket-major phi_bucket via loc (contiguous 128 B).
// PLANAR complex output: out[0..B-1] = log|det|, out[B..2B-1] = arg(sign)
// ---------------------------------------------------------------------------
__global__ __launch_bounds__(256) void k3_det(
    const float* __restrict__ phi_bucket, const int* __restrict__ loc,
    float* __restrict__ out)
{
  __shared__ float A[4][32 * 33];
  const int w = threadIdx.x >> 6;
  const int lane = threadIdx.x & 63;
  const int b = blockIdx.x * 4 + w;
  float* Aw = A[w];

  {
    const int jj = lane & 31;
    const int hi = lane >> 5;              // 0 or 1: ig halves
    int lcol = loc[b * 32 + jj];
    const float* colp = phi_bucket + (size_t)lcol * 32 + hi * 16;
    #pragma unroll
    for (int i = 0; i < 4; ++i) {
      float4 v = *(const float4*)(colp + i * 4);
      int ig = hi * 16 + i * 4;
      Aw[(ig + 0) * 33 + jj] = v.x;
      Aw[(ig + 1) * 33 + jj] = v.y;
      Aw[(ig + 2) * 33 + jj] = v.z;
      Aw[(ig + 3) * 33 + jj] = v.w;
    }
  }
  WAVE_SYNC();

  float logabs = 0.f;
  int negs = 0;
  for (int k = 0; k < 32; ++k) {
    // isamax over rows k..31 of column k (ties -> first index)
    float v = -1.f;
    int vi = lane;
    if (lane >= k && lane < 32) v = fabsf(Aw[lane * 33 + k]);
    #pragma unroll
    for (int off = 32; off > 0; off >>= 1) {
      float ov = __shfl_xor(v, off);
      int oi = __shfl_xor(vi, off);
      if (ov > v || (ov == v && oi < vi)) { v = ov; vi = oi; }
    }
    int p = vi;                          // uniform across the wave
    if (p != k) {
      negs ^= 1;
      if (lane < 32) {
        float tmp = Aw[k * 33 + lane];
        Aw[k * 33 + lane] = Aw[p * 33 + lane];
        Aw[p * 33 + lane] = tmp;
      }
    }
    WAVE_SYNC();
    float piv = Aw[k * 33 + k];
    if (piv < 0.f) negs ^= 1;
    logabs += logf(fabsf(piv));
    if (lane > k && lane < 32) {
      float l = Aw[lane * 33 + k];
      if (fabsf(piv) >= 1.17549435e-38f) l = l * (1.0f / piv);  // sscal path
      else                               l = l / piv;           // tiny pivot
      Aw[lane * 33 + k] = l;
    }
    WAVE_SYNC();
    {
      const int mid = (k + 33) >> 1;         // balanced split of k+1..31
      const int j   = lane & 31;
      const int ilo = (lane < 32) ? (k + 1) : mid;
      const int ihi = (lane < 32) ? mid : 32;
      if (j > k) {
        float nukj = -Aw[k * 33 + j];
        for (int i = ilo; i < ihi; ++i)
          Aw[i * 33 + j] = fmaf(nukj, Aw[i * 33 + k], Aw[i * 33 + j]);
      }
    }
    WAVE_SYNC();
  }

  if (lane == 0) {
    out[b]       = logabs;                                   // Re: log|det|
    out[B_N + b] = (negs & 1) ? 3.14159265358979f : 0.0f;    // Im: arg(sign)
  }
}

// ---------------------------------------------------------------------------
extern "C" void kernel_launch(void* const* d_in, const int* in_sizes, int n_in,
                              void* d_out, int out_size, void* d_ws, size_t ws_size,
                              hipStream_t stream) {
  const float* n   = (const float*)d_in[0];
  const float* Phi = (const float*)d_in[1];
  const float* W1  = (const float*)d_in[2];
  const float* b1  = (const float*)d_in[3];
  const float* W2  = (const float*)d_in[4];
  const float* b2  = (const float*)d_in[5];
  float* out = (float*)d_out;

  char* ws = (char*)d_ws;
  float*        h_ws       = (float*)ws;                                  // 8 MB
  float*        phi_bucket = (float*)(ws + (size_t)8  * 1024 * 1024);     // 16 MB
  float*        W2t        = (float*)(ws + (size_t)24 * 1024 * 1024);     // 8 MB
  unsigned int* mask       = (unsigned int*)(ws + (size_t)32 * 1024 * 1024); // 64 KB
  int*          bent       = (int*)(ws + (size_t)32 * 1024 * 1024 + 65536);  // 2 MB
  int*          loc        = (int*)(ws + (size_t)34 * 1024 * 1024 + 65536);  // 512 KB
  int*          bcnt       = (int*)(ws + (size_t)34 * 1024 * 1024 + 65536 + 524288);
  int*          boff       = (int*)(ws + (size_t)34 * 1024 * 1024 + 65536 + 524288 + 4096);

  hipLaunchKernelGGL(k_w2t, dim3(H_N), dim3(256), 0, stream, W2, W2t);
  hipLaunchKernelGGL(k1_idx_h, dim3(B_N), dim3(256), 0, stream,
                     n, W1, b1, h_ws, mask);
  hipLaunchKernelGGL(k_fill, dim3(M_N), dim3(256), 0, stream,
                     mask, bcnt, boff, bent, loc);
  hipLaunchKernelGGL(k2_gemm_gather, dim3(M_N, 16), dim3(128), 0, stream,
                     h_ws, W2t, b2, Phi, bcnt, boff, bent, phi_bucket);
  hipLaunchKernelGGL(k3_det, dim3(B_N / 4), dim3(256), 0, stream,
                     phi_bucket, loc, out);
}